// Round 1
// baseline (4658.248 us; speedup 1.0000x reference)
//
#include <hip/hip_runtime.h>

#define TT 2048
#define HD 64
#define NG 256

__device__ __forceinline__ float fsig(float x) {
    return 1.0f / (1.0f + __expf(-x));
}
__device__ __forceinline__ float ftanh(float x) {
    // 1 - 2/(1+e^{2x}); handles +-inf gracefully, ~1e-7 abs error near 0
    return 1.0f - 2.0f / (1.0f + __expf(2.0f * x));
}

__global__ __launch_bounds__(256, 2)
void lstm2_kernel(const float* __restrict__ x,
                  const float* __restrict__ Wih0,
                  const float* __restrict__ Whh0,
                  const float* __restrict__ bih0,
                  const float* __restrict__ bhh0,
                  const float* __restrict__ Wih1,
                  const float* __restrict__ Whh1,
                  const float* __restrict__ bih1,
                  const float* __restrict__ bhh1,
                  const float* __restrict__ fcW,
                  const float* __restrict__ fcb,
                  float* __restrict__ out)
{
    const int tid  = threadIdx.x;          // gate id g in [0,256)
    const int bid  = blockIdx.x;           // rows 2*bid, 2*bid+1
    const int row0 = 2 * bid;
    const int row1 = row0 + 1;

    __shared__ float h0s[2][HD];           // layer0 hidden (= layer1 input)
    __shared__ float h2s[2][HD];           // layer1 hidden
    __shared__ float g0s[2][NG];
    __shared__ float g1s[2][NG];

    // Register-resident weight rows for gate g = tid (192 VGPRs)
    float w0[HD], wi1[HD], wh1[HD];
    {
        const float4* W0 = (const float4*)(Whh0 + tid * HD);
        const float4* Wi = (const float4*)(Wih1 + tid * HD);
        const float4* Wh = (const float4*)(Whh1 + tid * HD);
        #pragma unroll
        for (int k4 = 0; k4 < HD / 4; ++k4) {
            float4 v = W0[k4];
            w0[4*k4+0] = v.x; w0[4*k4+1] = v.y; w0[4*k4+2] = v.z; w0[4*k4+3] = v.w;
            v = Wi[k4];
            wi1[4*k4+0] = v.x; wi1[4*k4+1] = v.y; wi1[4*k4+2] = v.z; wi1[4*k4+3] = v.w;
            v = Wh[k4];
            wh1[4*k4+0] = v.x; wh1[4*k4+1] = v.y; wh1[4*k4+2] = v.z; wh1[4*k4+3] = v.w;
        }
    }
    const float wx = Wih0[tid];
    const float b0 = bih0[tid] + bhh0[tid];
    const float b1 = bih1[tid] + bhh1[tid];

    const int r = tid >> 6;                // row (for elementwise threads)
    const int j = tid & 63;                // hidden unit
    if (tid < 2 * HD) {
        h0s[r][j] = 0.0f;
        h2s[r][j] = 0.0f;
    }
    float c0 = 0.0f, c1 = 0.0f, hlast = 0.0f;
    const float fcw = (tid < 2 * HD) ? fcW[j] : 0.0f;

    __syncthreads();

    float xv0 = x[row0 * TT];
    float xv1 = x[row1 * TT];

    const float4* h0a = (const float4*)(&h0s[0][0]);
    const float4* h0b = (const float4*)(&h0s[1][0]);
    const float4* h2a = (const float4*)(&h2s[0][0]);
    const float4* h2b = (const float4*)(&h2s[1][0]);

    for (int t = 0; t < TT; ++t) {
        // ---------- layer0 gates: a = x_t*wih0[g] + b0 + Whh0[g,:]*h0 ----------
        float a0  = __fmaf_rn(xv0, wx, b0);
        float a1  = __fmaf_rn(xv1, wx, b0);
        float a0b = 0.0f, a1b = 0.0f;

        {   // software-prefetch next step's x (uniform address -> scalar load)
            const int tn = (t + 1 < TT) ? (t + 1) : (TT - 1);
            xv0 = x[row0 * TT + tn];
            xv1 = x[row1 * TT + tn];
        }

        #pragma unroll
        for (int k4 = 0; k4 < 16; ++k4) {
            const float4 p = h0a[k4];      // broadcast ds_read_b128
            const float4 q = h0b[k4];
            const int k = 4 * k4;
            a0  = __fmaf_rn(w0[k+0], p.x, a0);
            a0b = __fmaf_rn(w0[k+1], p.y, a0b);
            a0  = __fmaf_rn(w0[k+2], p.z, a0);
            a0b = __fmaf_rn(w0[k+3], p.w, a0b);
            a1  = __fmaf_rn(w0[k+0], q.x, a1);
            a1b = __fmaf_rn(w0[k+1], q.y, a1b);
            a1  = __fmaf_rn(w0[k+2], q.z, a1);
            a1b = __fmaf_rn(w0[k+3], q.w, a1b);
        }
        g0s[0][tid] = a0 + a0b;
        g0s[1][tid] = a1 + a1b;
        __syncthreads();                   // barrier A

        // ---------- layer0 elementwise (threads 0..127) ----------
        if (tid < 128) {
            const float gi = g0s[r][j];
            const float gf = g0s[r][HD + j];
            const float gg = g0s[r][2 * HD + j];
            const float go = g0s[r][3 * HD + j];
            const float iv = fsig(gi);
            const float fv = fsig(gf);
            const float gv = ftanh(gg);
            const float ov = fsig(go);
            c0 = __fmaf_rn(fv, c0, iv * gv);
            h0s[r][j] = ov * ftanh(c0);
        }
        __syncthreads();                   // barrier B

        // ---------- layer1 gates: u = b1 + Wih1[g,:]*h1out + Whh1[g,:]*h2 ----------
        float u0 = b1,  u1 = b1;
        float u0b = 0.0f, u1b = 0.0f;
        float u0c = 0.0f, u1c = 0.0f;
        float u0d = 0.0f, u1d = 0.0f;
        #pragma unroll
        for (int k4 = 0; k4 < 16; ++k4) {
            const float4 p = h0a[k4];
            const float4 q = h0b[k4];
            const float4 m = h2a[k4];
            const float4 n = h2b[k4];
            const int k = 4 * k4;
            u0  = __fmaf_rn(wi1[k+0], p.x, u0);
            u0b = __fmaf_rn(wi1[k+1], p.y, u0b);
            u0  = __fmaf_rn(wi1[k+2], p.z, u0);
            u0b = __fmaf_rn(wi1[k+3], p.w, u0b);
            u0c = __fmaf_rn(wh1[k+0], m.x, u0c);
            u0d = __fmaf_rn(wh1[k+1], m.y, u0d);
            u0c = __fmaf_rn(wh1[k+2], m.z, u0c);
            u0d = __fmaf_rn(wh1[k+3], m.w, u0d);
            u1  = __fmaf_rn(wi1[k+0], q.x, u1);
            u1b = __fmaf_rn(wi1[k+1], q.y, u1b);
            u1  = __fmaf_rn(wi1[k+2], q.z, u1);
            u1b = __fmaf_rn(wi1[k+3], q.w, u1b);
            u1c = __fmaf_rn(wh1[k+0], n.x, u1c);
            u1d = __fmaf_rn(wh1[k+1], n.y, u1d);
            u1c = __fmaf_rn(wh1[k+2], n.z, u1c);
            u1d = __fmaf_rn(wh1[k+3], n.w, u1d);
        }
        g1s[0][tid] = (u0 + u0b) + (u0c + u0d);
        g1s[1][tid] = (u1 + u1b) + (u1c + u1d);
        __syncthreads();                   // barrier C

        // ---------- layer1 elementwise ----------
        if (tid < 128) {
            const float gi = g1s[r][j];
            const float gf = g1s[r][HD + j];
            const float gg = g1s[r][2 * HD + j];
            const float go = g1s[r][3 * HD + j];
            const float iv = fsig(gi);
            const float fv = fsig(gf);
            const float gv = ftanh(gg);
            const float ov = fsig(go);
            c1 = __fmaf_rn(fv, c1, iv * gv);
            hlast = ov * ftanh(c1);
            h2s[r][j] = hlast;
        }
        // no barrier: next-iter barriers A,B order the h2s write before its
        // next read (layer1 gates), and all other buffers are disjoint.
    }

    // ---------- final FC: out[row] = sum_j h2_last[row][j]*fcW[j] + fcb ----------
    if (tid < 128) {
        float p = hlast * fcw;
        #pragma unroll
        for (int off = 32; off > 0; off >>= 1)
            p += __shfl_xor(p, off, 64);
        if (j == 0) out[row0 + r] = p + fcb[0];
    }
}

extern "C" void kernel_launch(void* const* d_in, const int* in_sizes, int n_in,
                              void* d_out, int out_size, void* d_ws, size_t ws_size,
                              hipStream_t stream) {
    const float* x    = (const float*)d_in[0];
    const float* Wih0 = (const float*)d_in[1];
    const float* Whh0 = (const float*)d_in[2];
    const float* bih0 = (const float*)d_in[3];
    const float* bhh0 = (const float*)d_in[4];
    const float* Wih1 = (const float*)d_in[5];
    const float* Whh1 = (const float*)d_in[6];
    const float* bih1 = (const float*)d_in[7];
    const float* bhh1 = (const float*)d_in[8];
    const float* fcW  = (const float*)d_in[9];
    const float* fcb  = (const float*)d_in[10];
    float* out = (float*)d_out;

    lstm2_kernel<<<512, 256, 0, stream>>>(x, Wih0, Whh0, bih0, bhh0,
                                          Wih1, Whh1, bih1, bhh1,
                                          fcW, fcb, out);
}